// Round 11
// baseline (213.090 us; speedup 1.0000x reference)
//
#include <hip/hip_runtime.h>

#define T_ 2048
#define E_ 1024
#define H_ 16
#define D_ 64
#define M_ 4096   // B*T

typedef unsigned short ushort_t;
typedef __attribute__((ext_vector_type(8))) short bf16x8;
typedef __attribute__((ext_vector_type(4))) float f32x4;
typedef __attribute__((ext_vector_type(8))) unsigned short u16x8;
typedef __attribute__((ext_vector_type(2))) unsigned int u32x2;

__device__ __forceinline__ ushort_t f2bf(float f) {
  union { float f; unsigned u; } v; v.f = f;
  unsigned r = v.u + 0x7FFFu + ((v.u >> 16) & 1u);
  return (ushort_t)(r >> 16);
}

__device__ __forceinline__ void gl16(const void* g, void* l) {
  __builtin_amdgcn_global_load_lds((const __attribute__((address_space(1))) void*)g,
                                   (__attribute__((address_space(3))) void*)l, 16, 0, 0);
}

// ---------------- all f32->bf16 conversions in ONE launch ----------------
__global__ __launch_bounds__(256)
void conv_all(const float* __restrict__ x,  const float* __restrict__ wq,
              const float* __restrict__ wk, const float* __restrict__ wv,
              const float* __restrict__ wp,
              ushort_t* __restrict__ xb,  ushort_t* __restrict__ wqb,
              ushort_t* __restrict__ wkb, ushort_t* __restrict__ wvb,
              ushort_t* __restrict__ wpb)
{
  const int id = blockIdx.x;
  const float* s; ushort_t* d; size_t off;
  if (id < 2048) { s = x; d = xb; off = (size_t)id * 2048; }
  else {
    int wsel = (id - 2048) >> 9, wid = (id - 2048) & 511;
    off = (size_t)wid * 2048;
    s = wsel == 0 ? wq : wsel == 1 ? wk : wsel == 2 ? wv : wp;
    d = wsel == 0 ? wqb : wsel == 1 ? wkb : wsel == 2 ? wvb : wpb;
  }
  size_t i = off + (size_t)threadIdx.x * 8;
  float4 a = *(const float4*)(s + i);
  float4 b = *(const float4*)(s + i + 4);
  u16x8 o;
  o[0]=f2bf(a.x); o[1]=f2bf(a.y); o[2]=f2bf(a.z); o[3]=f2bf(a.w);
  o[4]=f2bf(b.x); o[5]=f2bf(b.y); o[6]=f2bf(b.z); o[7]=f2bf(b.w);
  *(u16x8*)(d + i) = o;
}

// ------- 128x128x(K=1024) bf16 GEMM core, Y = A @ W^T, 2-phase pipelined -------
__device__ __forceinline__ void gemm_core(const ushort_t* __restrict__ A,
                                          const ushort_t* __restrict__ W,
                                          int m0, int n0,
                                          ushort_t* As, ushort_t* Bs,
                                          f32x4 acc[4][4])
{
  const int t = threadIdx.x;
  const int lane = t & 63, w = t >> 6;
  const int g = lane >> 4, lq = lane & 15;
  const int wr = w >> 1, wc = w & 1;
  const int r0 = t >> 2;
  const int c0 = t & 3;
  const int ca0 = c0 ^ ((r0 >> 1) & 3);
  const int r1 = r0 + 64;
  const int ca1 = c0 ^ ((r1 >> 1) & 3);

  #pragma unroll
  for (int i = 0; i < 4; ++i)
    #pragma unroll
    for (int j = 0; j < 4; ++j) acc[i][j] = (f32x4){0.f,0.f,0.f,0.f};

  gl16(A + (size_t)(m0 + r0) * 1024 + ca0 * 8, As + t * 8);
  gl16(A + (size_t)(m0 + r1) * 1024 + ca1 * 8, As + 2048 + t * 8);
  gl16(W + (size_t)(n0 + r0) * 1024 + ca0 * 8, Bs + t * 8);
  gl16(W + (size_t)(n0 + r1) * 1024 + ca1 * 8, Bs + 2048 + t * 8);
  __syncthreads();

  int cur = 0;
  for (int k0 = 0; k0 < 1024; k0 += 32) {
    if (k0 + 32 < 1024) {
      const int nx = (cur ^ 1) * 4096;
      gl16(A + (size_t)(m0 + r0) * 1024 + k0 + 32 + ca0 * 8, As + nx + t * 8);
      gl16(A + (size_t)(m0 + r1) * 1024 + k0 + 32 + ca1 * 8, As + nx + 2048 + t * 8);
      gl16(W + (size_t)(n0 + r0) * 1024 + k0 + 32 + ca0 * 8, Bs + nx + t * 8);
      gl16(W + (size_t)(n0 + r1) * 1024 + k0 + 32 + ca1 * 8, Bs + nx + 2048 + t * 8);
    }
    const ushort_t* as = As + cur * 4096;
    const ushort_t* bs = Bs + cur * 4096;

    bf16x8 af[4], bfr[4];
    #pragma unroll
    for (int mi = 0; mi < 4; ++mi) {
      int row = wr * 64 + mi * 16 + lq;
      int ch = g ^ ((row >> 1) & 3);
      af[mi] = *(const bf16x8*)(as + row * 32 + ch * 8);
    }
    #pragma unroll
    for (int ni = 0; ni < 4; ++ni) {
      int row = wc * 64 + ni * 16 + lq;
      int ch = g ^ ((row >> 1) & 3);
      bfr[ni] = *(const bf16x8*)(bs + row * 32 + ch * 8);
    }
    __builtin_amdgcn_s_setprio(1);
    #pragma unroll
    for (int mi = 0; mi < 4; ++mi)
      #pragma unroll
      for (int ni = 0; ni < 4; ++ni)
        acc[mi][ni] = __builtin_amdgcn_mfma_f32_16x16x32_bf16(af[mi], bfr[ni], acc[mi][ni], 0, 0, 0);
    __builtin_amdgcn_s_setprio(0);

    __syncthreads();
    cur ^= 1;
  }
}

// Fused QKV projection. grid.x 0..23: sel = x>>3 (Q,K,V), n0 = (x&7)*128.
__global__ __launch_bounds__(256)
void gemm_qkv(const ushort_t* __restrict__ xb,
              const ushort_t* __restrict__ wqb, const ushort_t* __restrict__ wkb,
              const ushort_t* __restrict__ wvb,
              ushort_t* __restrict__ Qd, ushort_t* __restrict__ Kd, ushort_t* __restrict__ Vd)
{
  __shared__ __align__(16) ushort_t As[2 * 4096];
  __shared__ __align__(16) ushort_t Bs[2 * 4096];
  const int bx = blockIdx.x;
  const int sel = bx >> 3;
  const int n0 = (bx & 7) * 128;
  const int m0 = blockIdx.y * 128;
  const ushort_t* W = sel == 0 ? wqb : (sel == 1 ? wkb : wvb);
  f32x4 acc[4][4];
  gemm_core(xb, W, m0, n0, As, Bs, acc);

  const int t = threadIdx.x, lane = t & 63, w = t >> 6;
  const int g = lane >> 4, lq = lane & 15, wr = w >> 1, wc = w & 1;
  const float scl = (sel == 0) ? 0.125f : 1.0f;
  ushort_t* dst = sel == 0 ? Qd : (sel == 1 ? Kd : Vd);
  #pragma unroll
  for (int mi = 0; mi < 4; ++mi)
    #pragma unroll
    for (int ni = 0; ni < 4; ++ni)
      #pragma unroll
      for (int r = 0; r < 4; ++r) {
        int m = m0 + wr * 64 + mi * 16 + 4 * g + r;
        int n = n0 + wc * 64 + ni * 16 + lq;
        int b = m >> 11, tt = m & (T_ - 1);
        int h = n >> 6, d = n & (D_ - 1);
        ushort_t v = f2bf(acc[mi][ni][r] * scl);
        if (sel < 2) dst[((size_t)(b * H_ + h) * T_ + tt) * D_ + d] = v;
        else         dst[((size_t)(b * H_ + h) * D_ + d) * T_ + tt] = v;
      }
}

// Output projection, 64x128 tiles, 2-phase pipelined: out = Ab @ Wp^T + bp. grid (8, 64).
__global__ __launch_bounds__(256)
void gemm_out64(const ushort_t* __restrict__ Ab, const ushort_t* __restrict__ wpb,
                const float* __restrict__ bias, float* __restrict__ out)
{
  __shared__ __align__(16) ushort_t As[2 * 2048];
  __shared__ __align__(16) ushort_t Bs[2 * 4096];
  const int t = threadIdx.x, lane = t & 63, w = t >> 6;
  const int g = lane >> 4, lq = lane & 15;
  const int n0 = blockIdx.x * 128;
  const int m0 = blockIdx.y * 64;
  const int r0 = t >> 2, c0 = t & 3;
  const int ca0 = c0 ^ ((r0 >> 1) & 3);
  const int r1 = r0 + 64;
  const int ca1 = c0 ^ ((r1 >> 1) & 3);

  f32x4 acc[4][2];
  #pragma unroll
  for (int i = 0; i < 4; ++i) { acc[i][0] = (f32x4){0.f,0.f,0.f,0.f}; acc[i][1] = (f32x4){0.f,0.f,0.f,0.f}; }

  gl16(Ab  + (size_t)(m0 + r0) * 1024 + ca0 * 8, As + t * 8);
  gl16(wpb + (size_t)(n0 + r0) * 1024 + ca0 * 8, Bs + t * 8);
  gl16(wpb + (size_t)(n0 + r1) * 1024 + ca1 * 8, Bs + 2048 + t * 8);
  __syncthreads();

  int cur = 0;
  for (int k0 = 0; k0 < 1024; k0 += 32) {
    if (k0 + 32 < 1024) {
      gl16(Ab  + (size_t)(m0 + r0) * 1024 + k0 + 32 + ca0 * 8, As + (cur ^ 1) * 2048 + t * 8);
      gl16(wpb + (size_t)(n0 + r0) * 1024 + k0 + 32 + ca0 * 8, Bs + (cur ^ 1) * 4096 + t * 8);
      gl16(wpb + (size_t)(n0 + r1) * 1024 + k0 + 32 + ca1 * 8, Bs + (cur ^ 1) * 4096 + 2048 + t * 8);
    }
    const ushort_t* as = As + cur * 2048;
    const ushort_t* bs = Bs + cur * 4096;

    bf16x8 af[4], bfr[2];
    #pragma unroll
    for (int mi = 0; mi < 4; ++mi) {
      int row = mi * 16 + lq;
      int ch = g ^ ((row >> 1) & 3);
      af[mi] = *(const bf16x8*)(as + row * 32 + ch * 8);
    }
    #pragma unroll
    for (int ni = 0; ni < 2; ++ni) {
      int row = w * 32 + ni * 16 + lq;
      int ch = g ^ ((row >> 1) & 3);
      bfr[ni] = *(const bf16x8*)(bs + row * 32 + ch * 8);
    }
    __builtin_amdgcn_s_setprio(1);
    #pragma unroll
    for (int mi = 0; mi < 4; ++mi)
      #pragma unroll
      for (int ni = 0; ni < 2; ++ni)
        acc[mi][ni] = __builtin_amdgcn_mfma_f32_16x16x32_bf16(af[mi], bfr[ni], acc[mi][ni], 0, 0, 0);
    __builtin_amdgcn_s_setprio(0);

    __syncthreads();
    cur ^= 1;
  }
  #pragma unroll
  for (int mi = 0; mi < 4; ++mi)
    #pragma unroll
    for (int ni = 0; ni < 2; ++ni)
      #pragma unroll
      for (int r = 0; r < 4; ++r) {
        int m = m0 + mi * 16 + 4 * g + r;
        int n = n0 + w * 32 + ni * 16 + lq;
        out[(size_t)m * E_ + n] = acc[mi][ni][r] + bias[n];
      }
}

// ---------------- MFMA flash attention v7: QBLK=64, 16 q-rows/wave, 4 blocks/CU ----------------
// Per-wave math = R3-v1 verified structure (single sub-block); loads = v4 verified style
// (direct L1/L2, barrier-free). Grid 1024: qt = 31-(i>>5) (heavy first), bh = i&31
// (all q-tiles of a head land on one XCD under round-robin dispatch).
__global__ __launch_bounds__(256, 4)
void attn_mfma(const ushort_t* __restrict__ Q, const ushort_t* __restrict__ K,
               const ushort_t* __restrict__ Vt, ushort_t* __restrict__ O)
{
  __shared__ __align__(16) ushort_t Ps[64 * 72];
  const int t = threadIdx.x, w = t >> 6, lane = t & 63;
  const int g = lane >> 4, lq = lane & 15;
  const int i = blockIdx.x;
  const int qt = 31 - (i >> 5);          // 0..31, heavy tiles first
  const int bh = i & 31;
  const int q0 = qt * 64;
  const size_t qkbase = (size_t)bh * T_ * D_;
  const size_t vbase  = (size_t)bh * D_ * T_;

  // Q fragment for this wave's 16 q-rows (read once from global)
  const int rowA = 16 * w + lq;          // 0..63 within tile
  const int qgA = q0 + rowA;
  const bf16x8 qA0 = *(const bf16x8*)(Q + qkbase + (size_t)qgA * D_ + g * 8);
  const bf16x8 qA1 = *(const bf16x8*)(Q + qkbase + (size_t)qgA * D_ + 32 + g * 8);

  f32x4 acc[4];
  #pragma unroll
  for (int db = 0; db < 4; ++db) acc[db] = (f32x4){0.f,0.f,0.f,0.f};
  float mA = -1e30f, lA = 0.f;

  const int nt = qt + 1;

  for (int kt = 0; kt < nt; ++kt) {
    const int k0 = kt * 64;

    // K and V fragment loads (L1/L2-resident; compiler schedules/hoists)
    bf16x8 kf0[4], kf1[4], vf0[4], vf1[4];
    #pragma unroll
    for (int kb = 0; kb < 4; ++kb) {
      const ushort_t* kp = K + qkbase + (size_t)(k0 + kb * 16 + lq) * D_;
      kf0[kb] = *(const bf16x8*)(kp + g * 8);
      kf1[kb] = *(const bf16x8*)(kp + 32 + g * 8);
    }
    #pragma unroll
    for (int db = 0; db < 4; ++db) {
      const ushort_t* vp = Vt + vbase + (size_t)(db * 16 + lq) * T_ + k0;
      vf0[db] = *(const bf16x8*)(vp + g * 8);
      vf1[db] = *(const bf16x8*)(vp + 32 + g * 8);
    }

    // S^T = K . Q^T : lane holds q-row qgA, k = k0 + kb*16 + 4g + r
    f32x4 st[4];
    __builtin_amdgcn_s_setprio(1);
    #pragma unroll
    for (int kb = 0; kb < 4; ++kb) {
      f32x4 z = (f32x4){0.f,0.f,0.f,0.f};
      z = __builtin_amdgcn_mfma_f32_16x16x32_bf16(kf0[kb], qA0, z, 0, 0, 0);
      z = __builtin_amdgcn_mfma_f32_16x16x32_bf16(kf1[kb], qA1, z, 0, 0, 0);
      st[kb] = z;
    }
    __builtin_amdgcn_s_setprio(0);

    if (kt == nt - 1) {                  // only the diagonal tile masks
      #pragma unroll
      for (int kb = 0; kb < 4; ++kb)
        #pragma unroll
        for (int r = 0; r < 4; ++r) {
          int kg = k0 + kb * 16 + 4 * g + r;
          if (kg > qgA) st[kb][r] = -1e30f;
        }
    }

    float tm = -1e30f;
    #pragma unroll
    for (int kb = 0; kb < 4; ++kb)
      #pragma unroll
      for (int r = 0; r < 4; ++r) tm = fmaxf(tm, st[kb][r]);
    tm = fmaxf(tm, __shfl_xor(tm, 16));
    tm = fmaxf(tm, __shfl_xor(tm, 32));

    // defer-max: rescale only when a row's max grew by > 8 (wave-uniform branch)
    if (!__all(tm <= mA + 8.f)) {
      float mn = fmaxf(mA, tm);
      float al = __expf(mA - mn);
      mA = mn;
      lA *= al;
      float alr[4];
      #pragma unroll
      for (int r = 0; r < 4; ++r) alr[r] = __shfl(al, 4 * g + r);
      #pragma unroll
      for (int db = 0; db < 4; ++db)
        #pragma unroll
        for (int r = 0; r < 4; ++r) acc[db][r] *= alr[r];
    }

    float ts = 0.f;
    #pragma unroll
    for (int kb = 0; kb < 4; ++kb) {
      float p0 = __expf(st[kb][0] - mA), p1 = __expf(st[kb][1] - mA);
      float p2 = __expf(st[kb][2] - mA), p3 = __expf(st[kb][3] - mA);
      ts += (p0 + p1) + (p2 + p3);
      unsigned lo, hi;
      asm("v_cvt_pk_bf16_f32 %0, %1, %2" : "=v"(lo) : "v"(p0), "v"(p1));
      asm("v_cvt_pk_bf16_f32 %0, %1, %2" : "=v"(hi) : "v"(p2), "v"(p3));
      *(u32x2*)(Ps + rowA * 72 + kb * 16 + 4 * g) = (u32x2){lo, hi};
    }
    ts += __shfl_xor(ts, 16);
    ts += __shfl_xor(ts, 32);
    lA += ts;

    asm volatile("s_waitcnt lgkmcnt(0)" ::: "memory");   // own-wave Ps writes visible
    bf16x8 pa0 = *(const bf16x8*)(Ps + rowA * 72 + g * 8);
    bf16x8 pa1 = *(const bf16x8*)(Ps + rowA * 72 + 32 + g * 8);

    __builtin_amdgcn_s_setprio(1);
    #pragma unroll
    for (int db = 0; db < 4; ++db) {
      acc[db] = __builtin_amdgcn_mfma_f32_16x16x32_bf16(pa0, vf0[db], acc[db], 0, 0, 0);
      acc[db] = __builtin_amdgcn_mfma_f32_16x16x32_bf16(pa1, vf1[db], acc[db], 0, 0, 0);
    }
    __builtin_amdgcn_s_setprio(0);
  }

  float inv = 1.0f / lA;
  float li[4];
  #pragma unroll
  for (int r = 0; r < 4; ++r) li[r] = __shfl(inv, 4 * g + r);
  const int b = bh >> 4, h = bh & 15;
  #pragma unroll
  for (int db = 0; db < 4; ++db)
    #pragma unroll
    for (int r = 0; r < 4; ++r) {
      int mo = q0 + 16 * w + 4 * g + r;
      O[((size_t)(b * T_ + mo)) * E_ + h * 64 + db * 16 + lq] = f2bf(acc[db][r] * li[r]);
    }
}

extern "C" void kernel_launch(void* const* d_in, const int* in_sizes, int n_in,
                              void* d_out, int out_size, void* d_ws, size_t ws_size,
                              hipStream_t stream) {
  const float* x  = (const float*)d_in[0];
  const float* Wq = (const float*)d_in[1];
  const float* Wk = (const float*)d_in[2];
  const float* Wv = (const float*)d_in[3];
  const float* Wp = (const float*)d_in[4];
  const float* bp = (const float*)d_in[5];
  float* out = (float*)d_out;

  ushort_t* ws  = (ushort_t*)d_ws;
  ushort_t* xb  = ws;
  ushort_t* wqb = xb  + (size_t)M_ * E_;
  ushort_t* wkb = wqb + (size_t)E_ * E_;
  ushort_t* wvb = wkb + (size_t)E_ * E_;
  ushort_t* wpb = wvb + (size_t)E_ * E_;
  ushort_t* Qb  = wpb + (size_t)E_ * E_;
  ushort_t* Kb  = Qb  + (size_t)M_ * E_;
  ushort_t* Vb  = Kb  + (size_t)M_ * E_;
  ushort_t* Ab  = Vb  + (size_t)M_ * E_;

  conv_all<<<4096, 256, 0, stream>>>(x, Wq, Wk, Wv, Wp, xb, wqb, wkb, wvb, wpb);
  gemm_qkv<<<dim3(24, 32), 256, 0, stream>>>(xb, wqb, wkb, wvb, Qb, Kb, Vb);
  attn_mfma<<<1024, 256, 0, stream>>>(Qb, Kb, Vb, Ab);
  gemm_out64<<<dim3(8, 64), 256, 0, stream>>>(Ab, wpb, bp, out);
}

// Round 12
// 160.522 us; speedup vs baseline: 1.3275x; 1.3275x over previous
//
#include <hip/hip_runtime.h>

#define T_ 2048
#define E_ 1024
#define H_ 16
#define D_ 64
#define M_ 4096   // B*T

typedef unsigned short ushort_t;
typedef __attribute__((ext_vector_type(8))) short bf16x8;
typedef __attribute__((ext_vector_type(4))) float f32x4;
typedef __attribute__((ext_vector_type(8))) unsigned short u16x8;
typedef __attribute__((ext_vector_type(2))) unsigned int u32x2;

__device__ __forceinline__ ushort_t f2bf(float f) {
  union { float f; unsigned u; } v; v.f = f;
  unsigned r = v.u + 0x7FFFu + ((v.u >> 16) & 1u);
  return (ushort_t)(r >> 16);
}

__device__ __forceinline__ void gl16(const void* g, void* l) {
  __builtin_amdgcn_global_load_lds((const __attribute__((address_space(1))) void*)g,
                                   (__attribute__((address_space(3))) void*)l, 16, 0, 0);
}

// ---------------- all f32->bf16 conversions in ONE launch ----------------
__global__ __launch_bounds__(256)
void conv_all(const float* __restrict__ x,  const float* __restrict__ wq,
              const float* __restrict__ wk, const float* __restrict__ wv,
              const float* __restrict__ wp,
              ushort_t* __restrict__ xb,  ushort_t* __restrict__ wqb,
              ushort_t* __restrict__ wkb, ushort_t* __restrict__ wvb,
              ushort_t* __restrict__ wpb)
{
  const int id = blockIdx.x;
  const float* s; ushort_t* d; size_t off;
  if (id < 2048) { s = x; d = xb; off = (size_t)id * 2048; }
  else {
    int wsel = (id - 2048) >> 9, wid = (id - 2048) & 511;
    off = (size_t)wid * 2048;
    s = wsel == 0 ? wq : wsel == 1 ? wk : wsel == 2 ? wv : wp;
    d = wsel == 0 ? wqb : wsel == 1 ? wkb : wsel == 2 ? wvb : wpb;
  }
  size_t i = off + (size_t)threadIdx.x * 8;
  float4 a = *(const float4*)(s + i);
  float4 b = *(const float4*)(s + i + 4);
  u16x8 o;
  o[0]=f2bf(a.x); o[1]=f2bf(a.y); o[2]=f2bf(a.z); o[3]=f2bf(a.w);
  o[4]=f2bf(b.x); o[5]=f2bf(b.y); o[6]=f2bf(b.z); o[7]=f2bf(b.w);
  *(u16x8*)(d + i) = o;
}

// ------- 128x128x(K=1024) bf16 GEMM core, Y = A @ W^T, 2-phase pipelined -------
__device__ __forceinline__ void gemm_core(const ushort_t* __restrict__ A,
                                          const ushort_t* __restrict__ W,
                                          int m0, int n0,
                                          ushort_t* As, ushort_t* Bs,
                                          f32x4 acc[4][4])
{
  const int t = threadIdx.x;
  const int lane = t & 63, w = t >> 6;
  const int g = lane >> 4, lq = lane & 15;
  const int wr = w >> 1, wc = w & 1;
  const int r0 = t >> 2;
  const int c0 = t & 3;
  const int ca0 = c0 ^ ((r0 >> 1) & 3);
  const int r1 = r0 + 64;
  const int ca1 = c0 ^ ((r1 >> 1) & 3);

  #pragma unroll
  for (int i = 0; i < 4; ++i)
    #pragma unroll
    for (int j = 0; j < 4; ++j) acc[i][j] = (f32x4){0.f,0.f,0.f,0.f};

  gl16(A + (size_t)(m0 + r0) * 1024 + ca0 * 8, As + t * 8);
  gl16(A + (size_t)(m0 + r1) * 1024 + ca1 * 8, As + 2048 + t * 8);
  gl16(W + (size_t)(n0 + r0) * 1024 + ca0 * 8, Bs + t * 8);
  gl16(W + (size_t)(n0 + r1) * 1024 + ca1 * 8, Bs + 2048 + t * 8);
  __syncthreads();

  int cur = 0;
  for (int k0 = 0; k0 < 1024; k0 += 32) {
    if (k0 + 32 < 1024) {
      const int nx = (cur ^ 1) * 4096;
      gl16(A + (size_t)(m0 + r0) * 1024 + k0 + 32 + ca0 * 8, As + nx + t * 8);
      gl16(A + (size_t)(m0 + r1) * 1024 + k0 + 32 + ca1 * 8, As + nx + 2048 + t * 8);
      gl16(W + (size_t)(n0 + r0) * 1024 + k0 + 32 + ca0 * 8, Bs + nx + t * 8);
      gl16(W + (size_t)(n0 + r1) * 1024 + k0 + 32 + ca1 * 8, Bs + nx + 2048 + t * 8);
    }
    const ushort_t* as = As + cur * 4096;
    const ushort_t* bs = Bs + cur * 4096;

    bf16x8 af[4], bfr[4];
    #pragma unroll
    for (int mi = 0; mi < 4; ++mi) {
      int row = wr * 64 + mi * 16 + lq;
      int ch = g ^ ((row >> 1) & 3);
      af[mi] = *(const bf16x8*)(as + row * 32 + ch * 8);
    }
    #pragma unroll
    for (int ni = 0; ni < 4; ++ni) {
      int row = wc * 64 + ni * 16 + lq;
      int ch = g ^ ((row >> 1) & 3);
      bfr[ni] = *(const bf16x8*)(bs + row * 32 + ch * 8);
    }
    __builtin_amdgcn_s_setprio(1);
    #pragma unroll
    for (int mi = 0; mi < 4; ++mi)
      #pragma unroll
      for (int ni = 0; ni < 4; ++ni)
        acc[mi][ni] = __builtin_amdgcn_mfma_f32_16x16x32_bf16(af[mi], bfr[ni], acc[mi][ni], 0, 0, 0);
    __builtin_amdgcn_s_setprio(0);

    __syncthreads();
    cur ^= 1;
  }
}

// Fused QKV projection. grid.x 0..23: sel = x>>3 (Q,K,V), n0 = (x&7)*128.
__global__ __launch_bounds__(256)
void gemm_qkv(const ushort_t* __restrict__ xb,
              const ushort_t* __restrict__ wqb, const ushort_t* __restrict__ wkb,
              const ushort_t* __restrict__ wvb,
              ushort_t* __restrict__ Qd, ushort_t* __restrict__ Kd, ushort_t* __restrict__ Vd)
{
  __shared__ __align__(16) ushort_t As[2 * 4096];
  __shared__ __align__(16) ushort_t Bs[2 * 4096];
  const int bx = blockIdx.x;
  const int sel = bx >> 3;
  const int n0 = (bx & 7) * 128;
  const int m0 = blockIdx.y * 128;
  const ushort_t* W = sel == 0 ? wqb : (sel == 1 ? wkb : wvb);
  f32x4 acc[4][4];
  gemm_core(xb, W, m0, n0, As, Bs, acc);

  const int t = threadIdx.x, lane = t & 63, w = t >> 6;
  const int g = lane >> 4, lq = lane & 15, wr = w >> 1, wc = w & 1;
  const float scl = (sel == 0) ? 0.125f : 1.0f;
  ushort_t* dst = sel == 0 ? Qd : (sel == 1 ? Kd : Vd);
  #pragma unroll
  for (int mi = 0; mi < 4; ++mi)
    #pragma unroll
    for (int ni = 0; ni < 4; ++ni)
      #pragma unroll
      for (int r = 0; r < 4; ++r) {
        int m = m0 + wr * 64 + mi * 16 + 4 * g + r;
        int n = n0 + wc * 64 + ni * 16 + lq;
        int b = m >> 11, tt = m & (T_ - 1);
        int h = n >> 6, d = n & (D_ - 1);
        ushort_t v = f2bf(acc[mi][ni][r] * scl);
        if (sel < 2) dst[((size_t)(b * H_ + h) * T_ + tt) * D_ + d] = v;
        else         dst[((size_t)(b * H_ + h) * D_ + d) * T_ + tt] = v;
      }
}

// Output projection, 64x128 tiles, 2-phase pipelined: out = Ab @ Wp^T + bp. grid (8, 64).
__global__ __launch_bounds__(256)
void gemm_out64(const ushort_t* __restrict__ Ab, const ushort_t* __restrict__ wpb,
                const float* __restrict__ bias, float* __restrict__ out)
{
  __shared__ __align__(16) ushort_t As[2 * 2048];
  __shared__ __align__(16) ushort_t Bs[2 * 4096];
  const int t = threadIdx.x, lane = t & 63, w = t >> 6;
  const int g = lane >> 4, lq = lane & 15;
  const int n0 = blockIdx.x * 128;
  const int m0 = blockIdx.y * 64;
  const int r0 = t >> 2, c0 = t & 3;
  const int ca0 = c0 ^ ((r0 >> 1) & 3);
  const int r1 = r0 + 64;
  const int ca1 = c0 ^ ((r1 >> 1) & 3);

  f32x4 acc[4][2];
  #pragma unroll
  for (int i = 0; i < 4; ++i) { acc[i][0] = (f32x4){0.f,0.f,0.f,0.f}; acc[i][1] = (f32x4){0.f,0.f,0.f,0.f}; }

  gl16(Ab  + (size_t)(m0 + r0) * 1024 + ca0 * 8, As + t * 8);
  gl16(wpb + (size_t)(n0 + r0) * 1024 + ca0 * 8, Bs + t * 8);
  gl16(wpb + (size_t)(n0 + r1) * 1024 + ca1 * 8, Bs + 2048 + t * 8);
  __syncthreads();

  int cur = 0;
  for (int k0 = 0; k0 < 1024; k0 += 32) {
    if (k0 + 32 < 1024) {
      gl16(Ab  + (size_t)(m0 + r0) * 1024 + k0 + 32 + ca0 * 8, As + (cur ^ 1) * 2048 + t * 8);
      gl16(wpb + (size_t)(n0 + r0) * 1024 + k0 + 32 + ca0 * 8, Bs + (cur ^ 1) * 4096 + t * 8);
      gl16(wpb + (size_t)(n0 + r1) * 1024 + k0 + 32 + ca1 * 8, Bs + (cur ^ 1) * 4096 + 2048 + t * 8);
    }
    const ushort_t* as = As + cur * 2048;
    const ushort_t* bs = Bs + cur * 4096;

    bf16x8 af[4], bfr[2];
    #pragma unroll
    for (int mi = 0; mi < 4; ++mi) {
      int row = mi * 16 + lq;
      int ch = g ^ ((row >> 1) & 3);
      af[mi] = *(const bf16x8*)(as + row * 32 + ch * 8);
    }
    #pragma unroll
    for (int ni = 0; ni < 2; ++ni) {
      int row = w * 32 + ni * 16 + lq;
      int ch = g ^ ((row >> 1) & 3);
      bfr[ni] = *(const bf16x8*)(bs + row * 32 + ch * 8);
    }
    __builtin_amdgcn_s_setprio(1);
    #pragma unroll
    for (int mi = 0; mi < 4; ++mi)
      #pragma unroll
      for (int ni = 0; ni < 2; ++ni)
        acc[mi][ni] = __builtin_amdgcn_mfma_f32_16x16x32_bf16(af[mi], bfr[ni], acc[mi][ni], 0, 0, 0);
    __builtin_amdgcn_s_setprio(0);

    __syncthreads();
    cur ^= 1;
  }
  #pragma unroll
  for (int mi = 0; mi < 4; ++mi)
    #pragma unroll
    for (int ni = 0; ni < 2; ++ni)
      #pragma unroll
      for (int r = 0; r < 4; ++r) {
        int m = m0 + mi * 16 + 4 * g + r;
        int n = n0 + w * 32 + ni * 16 + lq;
        out[(size_t)m * E_ + n] = acc[mi][ni][r] + bias[n];
      }
}

// ---------------- MFMA flash attention v8: v4 per-wave math + k-split heavy tiles ----------------
// Jobs (grid 768): j<512 -> split: qt = 15-(j>>6) in 8..15, s=(j>>5)&1, bh=j&31,
//   k-tiles [s*(qt+1), (s+1)*(qt+1)); stores UNNORMALIZED f32 partials + per-row m,l.
// j>=512 -> unsplit: qt = 7-((j-512)>>5) in 0..7, bh=(j-512)&31, full range, writes Ab.
// Mask predicate per tile: kt >= 2*qt (same coverage as v4's nt-2).
__global__ __launch_bounds__(256, 3)
void attn_mfma(const ushort_t* __restrict__ Q, const ushort_t* __restrict__ K,
               const ushort_t* __restrict__ Vt, ushort_t* __restrict__ O,
               float* __restrict__ Op, float* __restrict__ Mp, float* __restrict__ Lp)
{
  __shared__ __align__(16) ushort_t Ps[128 * 72];
  const int t = threadIdx.x, w = t >> 6, lane = t & 63;
  const int g = lane >> 4, lq = lane & 15;
  const int j = blockIdx.x;
  int qt, bh, ks, ke;
  bool split;
  if (j < 512) {
    split = true;
    qt = 15 - (j >> 6);
    int s = (j >> 5) & 1;
    bh = j & 31;
    ks = s * (qt + 1);
    ke = ks + qt + 1;
  } else {
    split = false;
    qt = 7 - ((j - 512) >> 5);
    bh = (j - 512) & 31;
    ks = 0;
    ke = 2 * qt + 2;
  }
  const int q0 = qt * 128;
  const size_t qkbase = (size_t)bh * T_ * D_;
  const size_t vbase  = (size_t)bh * D_ * T_;

  const int rowA = 32 * w + lq, rowB = rowA + 16;
  const int qgA = q0 + rowA, qgB = q0 + rowB;
  const bf16x8 qA0 = *(const bf16x8*)(Q + qkbase + (size_t)qgA * D_ + g * 8);
  const bf16x8 qA1 = *(const bf16x8*)(Q + qkbase + (size_t)qgA * D_ + 32 + g * 8);
  const bf16x8 qB0 = *(const bf16x8*)(Q + qkbase + (size_t)qgB * D_ + g * 8);
  const bf16x8 qB1 = *(const bf16x8*)(Q + qkbase + (size_t)qgB * D_ + 32 + g * 8);

  f32x4 accA[4], accB[4];
  #pragma unroll
  for (int db = 0; db < 4; ++db) { accA[db] = (f32x4){0.f,0.f,0.f,0.f}; accB[db] = (f32x4){0.f,0.f,0.f,0.f}; }
  float mA = -1e30f, lA = 0.f, mB = -1e30f, lB = 0.f;

  for (int kt = ks; kt < ke; ++kt) {
    const int k0 = kt * 64;

    bf16x8 kf0[4], kf1[4], vf0[4], vf1[4];
    #pragma unroll
    for (int kb = 0; kb < 4; ++kb) {
      const ushort_t* kp = K + qkbase + (size_t)(k0 + kb * 16 + lq) * D_;
      kf0[kb] = *(const bf16x8*)(kp + g * 8);
      kf1[kb] = *(const bf16x8*)(kp + 32 + g * 8);
    }
    #pragma unroll
    for (int db = 0; db < 4; ++db) {
      const ushort_t* vp = Vt + vbase + (size_t)(db * 16 + lq) * T_ + k0;
      vf0[db] = *(const bf16x8*)(vp + g * 8);
      vf1[db] = *(const bf16x8*)(vp + 32 + g * 8);
    }

    f32x4 stA[4], stB[4];
    __builtin_amdgcn_s_setprio(1);
    #pragma unroll
    for (int kb = 0; kb < 4; ++kb) {
      f32x4 zA = (f32x4){0.f,0.f,0.f,0.f};
      zA = __builtin_amdgcn_mfma_f32_16x16x32_bf16(kf0[kb], qA0, zA, 0, 0, 0);
      zA = __builtin_amdgcn_mfma_f32_16x16x32_bf16(kf1[kb], qA1, zA, 0, 0, 0);
      stA[kb] = zA;
      f32x4 zB = (f32x4){0.f,0.f,0.f,0.f};
      zB = __builtin_amdgcn_mfma_f32_16x16x32_bf16(kf0[kb], qB0, zB, 0, 0, 0);
      zB = __builtin_amdgcn_mfma_f32_16x16x32_bf16(kf1[kb], qB1, zB, 0, 0, 0);
      stB[kb] = zB;
    }
    __builtin_amdgcn_s_setprio(0);

    if (kt >= 2 * qt) {                    // diagonal-adjacent tiles
      #pragma unroll
      for (int kb = 0; kb < 4; ++kb)
        #pragma unroll
        for (int r = 0; r < 4; ++r) {
          int kg = k0 + kb * 16 + 4 * g + r;
          if (kg > qgA) stA[kb][r] = -1e30f;
          if (kg > qgB) stB[kb][r] = -1e30f;
        }
    }

    float tmA = -1e30f, tmB = -1e30f;
    #pragma unroll
    for (int kb = 0; kb < 4; ++kb)
      #pragma unroll
      for (int r = 0; r < 4; ++r) { tmA = fmaxf(tmA, stA[kb][r]); tmB = fmaxf(tmB, stB[kb][r]); }
    tmA = fmaxf(tmA, __shfl_xor(tmA, 16)); tmA = fmaxf(tmA, __shfl_xor(tmA, 32));
    tmB = fmaxf(tmB, __shfl_xor(tmB, 16)); tmB = fmaxf(tmB, __shfl_xor(tmB, 32));

    if (!__all((tmA <= mA + 8.f) && (tmB <= mB + 8.f))) {
      float mnA = fmaxf(mA, tmA), mnB = fmaxf(mB, tmB);
      float alA = __expf(mA - mnA), alB = __expf(mB - mnB);
      mA = mnA; mB = mnB;
      lA *= alA; lB *= alB;
      float alAr[4], alBr[4];
      #pragma unroll
      for (int r = 0; r < 4; ++r) { alAr[r] = __shfl(alA, 4 * g + r); alBr[r] = __shfl(alB, 4 * g + r); }
      #pragma unroll
      for (int db = 0; db < 4; ++db)
        #pragma unroll
        for (int r = 0; r < 4; ++r) { accA[db][r] *= alAr[r]; accB[db][r] *= alBr[r]; }
    }

    float tsA = 0.f, tsB = 0.f;
    #pragma unroll
    for (int kb = 0; kb < 4; ++kb) {
      float pA0 = __expf(stA[kb][0] - mA), pA1 = __expf(stA[kb][1] - mA);
      float pA2 = __expf(stA[kb][2] - mA), pA3 = __expf(stA[kb][3] - mA);
      float pB0 = __expf(stB[kb][0] - mB), pB1 = __expf(stB[kb][1] - mB);
      float pB2 = __expf(stB[kb][2] - mB), pB3 = __expf(stB[kb][3] - mB);
      tsA += (pA0 + pA1) + (pA2 + pA3);
      tsB += (pB0 + pB1) + (pB2 + pB3);
      unsigned aLo, aHi, bLo, bHi;
      asm("v_cvt_pk_bf16_f32 %0, %1, %2" : "=v"(aLo) : "v"(pA0), "v"(pA1));
      asm("v_cvt_pk_bf16_f32 %0, %1, %2" : "=v"(aHi) : "v"(pA2), "v"(pA3));
      asm("v_cvt_pk_bf16_f32 %0, %1, %2" : "=v"(bLo) : "v"(pB0), "v"(pB1));
      asm("v_cvt_pk_bf16_f32 %0, %1, %2" : "=v"(bHi) : "v"(pB2), "v"(pB3));
      *(u32x2*)(Ps + rowA * 72 + kb * 16 + 4 * g) = (u32x2){aLo, aHi};
      *(u32x2*)(Ps + rowB * 72 + kb * 16 + 4 * g) = (u32x2){bLo, bHi};
    }
    tsA += __shfl_xor(tsA, 16); tsA += __shfl_xor(tsA, 32);
    tsB += __shfl_xor(tsB, 16); tsB += __shfl_xor(tsB, 32);
    lA += tsA; lB += tsB;

    asm volatile("s_waitcnt lgkmcnt(0)" ::: "memory");
    bf16x8 paA0 = *(const bf16x8*)(Ps + rowA * 72 + g * 8);
    bf16x8 paA1 = *(const bf16x8*)(Ps + rowA * 72 + 32 + g * 8);
    bf16x8 paB0 = *(const bf16x8*)(Ps + rowB * 72 + g * 8);
    bf16x8 paB1 = *(const bf16x8*)(Ps + rowB * 72 + 32 + g * 8);

    __builtin_amdgcn_s_setprio(1);
    #pragma unroll
    for (int db = 0; db < 4; ++db) {
      accA[db] = __builtin_amdgcn_mfma_f32_16x16x32_bf16(paA0, vf0[db], accA[db], 0, 0, 0);
      accA[db] = __builtin_amdgcn_mfma_f32_16x16x32_bf16(paA1, vf1[db], accA[db], 0, 0, 0);
      accB[db] = __builtin_amdgcn_mfma_f32_16x16x32_bf16(paB0, vf0[db], accB[db], 0, 0, 0);
      accB[db] = __builtin_amdgcn_mfma_f32_16x16x32_bf16(paB1, vf1[db], accB[db], 0, 0, 0);
    }
    __builtin_amdgcn_s_setprio(0);
  }

  if (split) {
    // store unnormalized partials: Op[j][row][col] f32; m,l per row (lane g==0 writes)
    float* op = Op + (size_t)j * 128 * 64;
    #pragma unroll
    for (int db = 0; db < 4; ++db)
      #pragma unroll
      for (int r = 0; r < 4; ++r) {
        int rA = 32 * w + 4 * g + r;
        op[rA * 64 + db * 16 + lq] = accA[db][r];
        op[(rA + 16) * 64 + db * 16 + lq] = accB[db][r];
      }
    if (g == 0) {
      Mp[j * 128 + rowA] = mA;  Lp[j * 128 + rowA] = lA;
      Mp[j * 128 + rowB] = mB;  Lp[j * 128 + rowB] = lB;
    }
  } else {
    float invA = 1.0f / lA, invB = 1.0f / lB;
    float liA[4], liB[4];
    #pragma unroll
    for (int r = 0; r < 4; ++r) { liA[r] = __shfl(invA, 4 * g + r); liB[r] = __shfl(invB, 4 * g + r); }
    const int b = bh >> 4, h = bh & 15;
    #pragma unroll
    for (int db = 0; db < 4; ++db)
      #pragma unroll
      for (int r = 0; r < 4; ++r) {
        int mAo = q0 + 32 * w + 4 * g + r;
        int mBo = mAo + 16;
        O[((size_t)(b * T_ + mAo)) * E_ + h * 64 + db * 16 + lq] = f2bf(accA[db][r] * liA[r]);
        O[((size_t)(b * T_ + mBo)) * E_ + h * 64 + db * 16 + lq] = f2bf(accB[db][r] * liB[r]);
      }
  }
}

// ---------------- flash-combine merge for split (qt>=8) tiles ----------------
// grid 256: mb -> qt = 15-(mb>>5), bh = mb&31; j0 = (15-qt)*64 + bh, j1 = j0 + 32.
__global__ __launch_bounds__(256)
void merge_attn(const float* __restrict__ Op, const float* __restrict__ Mp,
                const float* __restrict__ Lp, ushort_t* __restrict__ O)
{
  const int mb = blockIdx.x;
  const int grp = mb >> 5;            // 0..7 -> qt = 15-grp
  const int qt = 15 - grp;
  const int bh = mb & 31;
  const int j0 = grp * 64 + bh;
  const int j1 = j0 + 32;
  const int q0 = qt * 128;
  const int b = bh >> 4, h = bh & 15;

  const int tid = threadIdx.x;
  const int row = tid >> 1;
  const int ch = (tid & 1) * 32;

  const float m0 = Mp[j0 * 128 + row], l0 = Lp[j0 * 128 + row];
  const float m1 = Mp[j1 * 128 + row], l1 = Lp[j1 * 128 + row];
  const float m = fmaxf(m0, m1);
  const float c0 = __expf(m0 - m), c1 = __expf(m1 - m);
  const float inv = 1.0f / (l0 * c0 + l1 * c1);

  const float* p0 = Op + (size_t)j0 * 128 * 64 + row * 64 + ch;
  const float* p1 = Op + (size_t)j1 * 128 * 64 + row * 64 + ch;
  ushort_t* dst = O + ((size_t)(b * T_ + q0 + row)) * E_ + h * 64 + ch;
  #pragma unroll
  for (int c = 0; c < 32; c += 4) {
    float4 a0 = *(const float4*)(p0 + c);
    float4 a1 = *(const float4*)(p1 + c);
    dst[c + 0] = f2bf((a0.x * c0 + a1.x * c1) * inv);
    dst[c + 1] = f2bf((a0.y * c0 + a1.y * c1) * inv);
    dst[c + 2] = f2bf((a0.z * c0 + a1.z * c1) * inv);
    dst[c + 3] = f2bf((a0.w * c0 + a1.w * c1) * inv);
  }
}

extern "C" void kernel_launch(void* const* d_in, const int* in_sizes, int n_in,
                              void* d_out, int out_size, void* d_ws, size_t ws_size,
                              hipStream_t stream) {
  const float* x  = (const float*)d_in[0];
  const float* Wq = (const float*)d_in[1];
  const float* Wk = (const float*)d_in[2];
  const float* Wv = (const float*)d_in[3];
  const float* Wp = (const float*)d_in[4];
  const float* bp = (const float*)d_in[5];
  float* out = (float*)d_out;

  ushort_t* ws  = (ushort_t*)d_ws;
  ushort_t* xb  = ws;
  ushort_t* wqb = xb  + (size_t)M_ * E_;
  ushort_t* wkb = wqb + (size_t)E_ * E_;
  ushort_t* wvb = wkb + (size_t)E_ * E_;
  ushort_t* wpb = wvb + (size_t)E_ * E_;
  ushort_t* Qb  = wpb + (size_t)E_ * E_;
  ushort_t* Kb  = Qb  + (size_t)M_ * E_;
  ushort_t* Vb  = Kb  + (size_t)M_ * E_;
  ushort_t* Ab  = Vb  + (size_t)M_ * E_;
  // f32 partials after Ab (16.78 MB); m/l alias over dead xb region (attn no longer reads xb)
  float* Op = (float*)(Ab + (size_t)M_ * E_);          // 512*128*64 f32
  float* Mp = (float*)xb;                              // 512*128 f32 (aliases xb, dead after qkv)
  float* Lp = Mp + 512 * 128;

  conv_all<<<4096, 256, 0, stream>>>(x, Wq, Wk, Wv, Wp, xb, wqb, wkb, wvb, wpb);
  gemm_qkv<<<dim3(24, 32), 256, 0, stream>>>(xb, wqb, wkb, wvb, Qb, Kb, Vb);
  attn_mfma<<<768, 256, 0, stream>>>(Qb, Kb, Vb, Ab, Op, Mp, Lp);
  merge_attn<<<256, 256, 0, stream>>>(Op, Mp, Lp, Ab);
  gemm_out64<<<dim3(8, 64), 256, 0, stream>>>(Ab, wpb, bp, out);
}

// Round 13
// 135.671 us; speedup vs baseline: 1.5706x; 1.1832x over previous
//
#include <hip/hip_runtime.h>

#define T_ 2048
#define E_ 1024
#define H_ 16
#define D_ 64
#define M_ 4096   // B*T

typedef unsigned short ushort_t;
typedef __attribute__((ext_vector_type(8))) short bf16x8;
typedef __attribute__((ext_vector_type(4))) float f32x4;
typedef __attribute__((ext_vector_type(8))) unsigned short u16x8;
typedef __attribute__((ext_vector_type(2))) unsigned int u32x2;

__device__ __forceinline__ ushort_t f2bf(float f) {
  union { float f; unsigned u; } v; v.f = f;
  unsigned r = v.u + 0x7FFFu + ((v.u >> 16) & 1u);
  return (ushort_t)(r >> 16);
}

__device__ __forceinline__ void gl16(const void* g, void* l) {
  __builtin_amdgcn_global_load_lds((const __attribute__((address_space(1))) void*)g,
                                   (__attribute__((address_space(3))) void*)l, 16, 0, 0);
}

// ---------------- all f32->bf16 conversions in ONE launch ----------------
__global__ __launch_bounds__(256)
void conv_all(const float* __restrict__ x,  const float* __restrict__ wq,
              const float* __restrict__ wk, const float* __restrict__ wv,
              const float* __restrict__ wp,
              ushort_t* __restrict__ xb,  ushort_t* __restrict__ wqb,
              ushort_t* __restrict__ wkb, ushort_t* __restrict__ wvb,
              ushort_t* __restrict__ wpb)
{
  const int id = blockIdx.x;
  const float* s; ushort_t* d; size_t off;
  if (id < 2048) { s = x; d = xb; off = (size_t)id * 2048; }
  else {
    int wsel = (id - 2048) >> 9, wid = (id - 2048) & 511;
    off = (size_t)wid * 2048;
    s = wsel == 0 ? wq : wsel == 1 ? wk : wsel == 2 ? wv : wp;
    d = wsel == 0 ? wqb : wsel == 1 ? wkb : wsel == 2 ? wvb : wpb;
  }
  size_t i = off + (size_t)threadIdx.x * 8;
  float4 a = *(const float4*)(s + i);
  float4 b = *(const float4*)(s + i + 4);
  u16x8 o;
  o[0]=f2bf(a.x); o[1]=f2bf(a.y); o[2]=f2bf(a.z); o[3]=f2bf(a.w);
  o[4]=f2bf(b.x); o[5]=f2bf(b.y); o[6]=f2bf(b.z); o[7]=f2bf(b.w);
  *(u16x8*)(d + i) = o;
}

// ------- 128x128x(K=1024) bf16 GEMM core, Y = A @ W^T, 2-phase pipelined -------
__device__ __forceinline__ void gemm_core(const ushort_t* __restrict__ A,
                                          const ushort_t* __restrict__ W,
                                          int m0, int n0,
                                          ushort_t* As, ushort_t* Bs,
                                          f32x4 acc[4][4])
{
  const int t = threadIdx.x;
  const int lane = t & 63, w = t >> 6;
  const int g = lane >> 4, lq = lane & 15;
  const int wr = w >> 1, wc = w & 1;
  const int r0 = t >> 2;
  const int c0 = t & 3;
  const int ca0 = c0 ^ ((r0 >> 1) & 3);
  const int r1 = r0 + 64;
  const int ca1 = c0 ^ ((r1 >> 1) & 3);

  #pragma unroll
  for (int i = 0; i < 4; ++i)
    #pragma unroll
    for (int j = 0; j < 4; ++j) acc[i][j] = (f32x4){0.f,0.f,0.f,0.f};

  gl16(A + (size_t)(m0 + r0) * 1024 + ca0 * 8, As + t * 8);
  gl16(A + (size_t)(m0 + r1) * 1024 + ca1 * 8, As + 2048 + t * 8);
  gl16(W + (size_t)(n0 + r0) * 1024 + ca0 * 8, Bs + t * 8);
  gl16(W + (size_t)(n0 + r1) * 1024 + ca1 * 8, Bs + 2048 + t * 8);
  __syncthreads();

  int cur = 0;
  for (int k0 = 0; k0 < 1024; k0 += 32) {
    if (k0 + 32 < 1024) {
      const int nx = (cur ^ 1) * 4096;
      gl16(A + (size_t)(m0 + r0) * 1024 + k0 + 32 + ca0 * 8, As + nx + t * 8);
      gl16(A + (size_t)(m0 + r1) * 1024 + k0 + 32 + ca1 * 8, As + nx + 2048 + t * 8);
      gl16(W + (size_t)(n0 + r0) * 1024 + k0 + 32 + ca0 * 8, Bs + nx + t * 8);
      gl16(W + (size_t)(n0 + r1) * 1024 + k0 + 32 + ca1 * 8, Bs + nx + 2048 + t * 8);
    }
    const ushort_t* as = As + cur * 4096;
    const ushort_t* bs = Bs + cur * 4096;

    bf16x8 af[4], bfr[4];
    #pragma unroll
    for (int mi = 0; mi < 4; ++mi) {
      int row = wr * 64 + mi * 16 + lq;
      int ch = g ^ ((row >> 1) & 3);
      af[mi] = *(const bf16x8*)(as + row * 32 + ch * 8);
    }
    #pragma unroll
    for (int ni = 0; ni < 4; ++ni) {
      int row = wc * 64 + ni * 16 + lq;
      int ch = g ^ ((row >> 1) & 3);
      bfr[ni] = *(const bf16x8*)(bs + row * 32 + ch * 8);
    }
    __builtin_amdgcn_s_setprio(1);
    #pragma unroll
    for (int mi = 0; mi < 4; ++mi)
      #pragma unroll
      for (int ni = 0; ni < 4; ++ni)
        acc[mi][ni] = __builtin_amdgcn_mfma_f32_16x16x32_bf16(af[mi], bfr[ni], acc[mi][ni], 0, 0, 0);
    __builtin_amdgcn_s_setprio(0);

    __syncthreads();
    cur ^= 1;
  }
}

// Fused QKV projection. grid.x 0..23: sel = x>>3 (Q,K,V), n0 = (x&7)*128.
__global__ __launch_bounds__(256)
void gemm_qkv(const ushort_t* __restrict__ xb,
              const ushort_t* __restrict__ wqb, const ushort_t* __restrict__ wkb,
              const ushort_t* __restrict__ wvb,
              ushort_t* __restrict__ Qd, ushort_t* __restrict__ Kd, ushort_t* __restrict__ Vd)
{
  __shared__ __align__(16) ushort_t As[2 * 4096];
  __shared__ __align__(16) ushort_t Bs[2 * 4096];
  const int bx = blockIdx.x;
  const int sel = bx >> 3;
  const int n0 = (bx & 7) * 128;
  const int m0 = blockIdx.y * 128;
  const ushort_t* W = sel == 0 ? wqb : (sel == 1 ? wkb : wvb);
  f32x4 acc[4][4];
  gemm_core(xb, W, m0, n0, As, Bs, acc);

  const int t = threadIdx.x, lane = t & 63, w = t >> 6;
  const int g = lane >> 4, lq = lane & 15, wr = w >> 1, wc = w & 1;
  const float scl = (sel == 0) ? 0.125f : 1.0f;
  ushort_t* dst = sel == 0 ? Qd : (sel == 1 ? Kd : Vd);
  #pragma unroll
  for (int mi = 0; mi < 4; ++mi)
    #pragma unroll
    for (int ni = 0; ni < 4; ++ni)
      #pragma unroll
      for (int r = 0; r < 4; ++r) {
        int m = m0 + wr * 64 + mi * 16 + 4 * g + r;
        int n = n0 + wc * 64 + ni * 16 + lq;
        int b = m >> 11, tt = m & (T_ - 1);
        int h = n >> 6, d = n & (D_ - 1);
        ushort_t v = f2bf(acc[mi][ni][r] * scl);
        if (sel < 2) dst[((size_t)(b * H_ + h) * T_ + tt) * D_ + d] = v;
        else         dst[((size_t)(b * H_ + h) * D_ + d) * T_ + tt] = v;
      }
}

// Output projection, 64x128 tiles, 2-phase pipelined: out = Ab @ Wp^T + bp. grid (8, 64).
__global__ __launch_bounds__(256)
void gemm_out64(const ushort_t* __restrict__ Ab, const ushort_t* __restrict__ wpb,
                const float* __restrict__ bias, float* __restrict__ out)
{
  __shared__ __align__(16) ushort_t As[2 * 2048];
  __shared__ __align__(16) ushort_t Bs[2 * 4096];
  const int t = threadIdx.x, lane = t & 63, w = t >> 6;
  const int g = lane >> 4, lq = lane & 15;
  const int n0 = blockIdx.x * 128;
  const int m0 = blockIdx.y * 64;
  const int r0 = t >> 2, c0 = t & 3;
  const int ca0 = c0 ^ ((r0 >> 1) & 3);
  const int r1 = r0 + 64;
  const int ca1 = c0 ^ ((r1 >> 1) & 3);

  f32x4 acc[4][2];
  #pragma unroll
  for (int i = 0; i < 4; ++i) { acc[i][0] = (f32x4){0.f,0.f,0.f,0.f}; acc[i][1] = (f32x4){0.f,0.f,0.f,0.f}; }

  gl16(Ab  + (size_t)(m0 + r0) * 1024 + ca0 * 8, As + t * 8);
  gl16(wpb + (size_t)(n0 + r0) * 1024 + ca0 * 8, Bs + t * 8);
  gl16(wpb + (size_t)(n0 + r1) * 1024 + ca1 * 8, Bs + 2048 + t * 8);
  __syncthreads();

  int cur = 0;
  for (int k0 = 0; k0 < 1024; k0 += 32) {
    if (k0 + 32 < 1024) {
      gl16(Ab  + (size_t)(m0 + r0) * 1024 + k0 + 32 + ca0 * 8, As + (cur ^ 1) * 2048 + t * 8);
      gl16(wpb + (size_t)(n0 + r0) * 1024 + k0 + 32 + ca0 * 8, Bs + (cur ^ 1) * 4096 + t * 8);
      gl16(wpb + (size_t)(n0 + r1) * 1024 + k0 + 32 + ca1 * 8, Bs + (cur ^ 1) * 4096 + 2048 + t * 8);
    }
    const ushort_t* as = As + cur * 2048;
    const ushort_t* bs = Bs + cur * 4096;

    bf16x8 af[4], bfr[2];
    #pragma unroll
    for (int mi = 0; mi < 4; ++mi) {
      int row = mi * 16 + lq;
      int ch = g ^ ((row >> 1) & 3);
      af[mi] = *(const bf16x8*)(as + row * 32 + ch * 8);
    }
    #pragma unroll
    for (int ni = 0; ni < 2; ++ni) {
      int row = w * 32 + ni * 16 + lq;
      int ch = g ^ ((row >> 1) & 3);
      bfr[ni] = *(const bf16x8*)(bs + row * 32 + ch * 8);
    }
    __builtin_amdgcn_s_setprio(1);
    #pragma unroll
    for (int mi = 0; mi < 4; ++mi)
      #pragma unroll
      for (int ni = 0; ni < 2; ++ni)
        acc[mi][ni] = __builtin_amdgcn_mfma_f32_16x16x32_bf16(af[mi], bfr[ni], acc[mi][ni], 0, 0, 0);
    __builtin_amdgcn_s_setprio(0);

    __syncthreads();
    cur ^= 1;
  }
  #pragma unroll
  for (int mi = 0; mi < 4; ++mi)
    #pragma unroll
    for (int ni = 0; ni < 2; ++ni)
      #pragma unroll
      for (int r = 0; r < 4; ++r) {
        int m = m0 + mi * 16 + 4 * g + r;
        int n = n0 + w * 32 + ni * 16 + lq;
        out[(size_t)m * E_ + n] = acc[mi][ni][r] + bias[n];
      }
}

// ---------------- MFMA flash attention v9: v4 + FORCED batch load residency ----------------
// Same math/indexing as R9-passing v4. New: keep-alive asm fences create hard data deps
// so K/V fragment loads issue early, wait ONCE as a pipelined batch (not 16 serial
// per-use waits), and stay VGPR-resident. K double-buffered across steps (fenced at
// step end -> covered by softmax+PV); V fenced just before PV (covered by softmax).
__global__ __launch_bounds__(256, 2)
void attn_mfma(const ushort_t* __restrict__ Q, const ushort_t* __restrict__ K,
               const ushort_t* __restrict__ Vt, ushort_t* __restrict__ O)
{
  __shared__ __align__(16) ushort_t Ps[128 * 72];
  const int t = threadIdx.x, w = t >> 6, lane = t & 63;
  const int g = lane >> 4, lq = lane & 15;
  const int i = blockIdx.x;
  const int xcd = i & 7, chunk = i >> 3;
  const int bh = xcd * 4 + (chunk >> 4);
  const int qt = (chunk < 32) ? (chunk & 15) : (15 - (chunk & 15));
  const int q0 = qt * 128;
  const size_t qkbase = (size_t)bh * T_ * D_;
  const size_t vbase  = (size_t)bh * D_ * T_;

  const int rowA = 32 * w + lq, rowB = rowA + 16;
  const int qgA = q0 + rowA, qgB = q0 + rowB;
  const bf16x8 qA0 = *(const bf16x8*)(Q + qkbase + (size_t)qgA * D_ + g * 8);
  const bf16x8 qA1 = *(const bf16x8*)(Q + qkbase + (size_t)qgA * D_ + 32 + g * 8);
  const bf16x8 qB0 = *(const bf16x8*)(Q + qkbase + (size_t)qgB * D_ + g * 8);
  const bf16x8 qB1 = *(const bf16x8*)(Q + qkbase + (size_t)qgB * D_ + 32 + g * 8);

  f32x4 accA[4], accB[4];
  #pragma unroll
  for (int db = 0; db < 4; ++db) { accA[db] = (f32x4){0.f,0.f,0.f,0.f}; accB[db] = (f32x4){0.f,0.f,0.f,0.f}; }
  float mA = -1e30f, lA = 0.f, mB = -1e30f, lB = 0.f;

  const int nt = 2 * qt + 2;   // always even

  bf16x8 kfa0[4], kfa1[4], kfb0[4], kfb1[4];   // K: double-buffered reg sets
  bf16x8 vf0[4], vf1[4];                       // V: loaded early each step

// keep-alive fence: consumes 8 fragments -> loads can't sink below; ONE batched wait
#define FENCE8(A_, B_)                                                          \
  asm volatile("" :: "v"(A_[0]), "v"(A_[1]), "v"(A_[2]), "v"(A_[3]),            \
                     "v"(B_[0]), "v"(B_[1]), "v"(B_[2]), "v"(B_[3]))

#define LOADK(K0_, KF0_, KF1_)                                                \
  do {                                                                        \
    _Pragma("unroll")                                                         \
    for (int _i = 0; _i < 4; ++_i) {                                          \
      const ushort_t* _kp = K + qkbase + (size_t)((K0_) + _i * 16 + lq) * D_; \
      KF0_[_i] = *(const bf16x8*)(_kp + g * 8);                               \
      KF1_[_i] = *(const bf16x8*)(_kp + 32 + g * 8);                          \
    }                                                                         \
  } while (0)

#define LOADV(K0_)                                                              \
  do {                                                                          \
    _Pragma("unroll")                                                           \
    for (int _i = 0; _i < 4; ++_i) {                                            \
      const ushort_t* _vp = Vt + vbase + (size_t)(_i * 16 + lq) * T_ + (K0_);   \
      vf0[_i] = *(const bf16x8*)(_vp + g * 8);                                  \
      vf1[_i] = *(const bf16x8*)(_vp + 32 + g * 8);                             \
    }                                                                           \
  } while (0)

#define STEP(K0_, KF0_, KF1_, KN0_, NKF0_, NKF1_, DOMASK)                       \
  do {                                                                          \
    const int _k0 = (K0_);                                                      \
    f32x4 stA[4], stB[4];                                                       \
    __builtin_amdgcn_s_setprio(1);                                              \
    _Pragma("unroll")                                                           \
    for (int _kb = 0; _kb < 4; ++_kb) {                                         \
      f32x4 zA = (f32x4){0.f,0.f,0.f,0.f};                                      \
      zA = __builtin_amdgcn_mfma_f32_16x16x32_bf16(KF0_[_kb], qA0, zA, 0, 0, 0);\
      zA = __builtin_amdgcn_mfma_f32_16x16x32_bf16(KF1_[_kb], qA1, zA, 0, 0, 0);\
      stA[_kb] = zA;                                                            \
      f32x4 zB = (f32x4){0.f,0.f,0.f,0.f};                                      \
      zB = __builtin_amdgcn_mfma_f32_16x16x32_bf16(KF0_[_kb], qB0, zB, 0, 0, 0);\
      zB = __builtin_amdgcn_mfma_f32_16x16x32_bf16(KF1_[_kb], qB1, zB, 0, 0, 0);\
      stB[_kb] = zB;                                                            \
    }                                                                           \
    __builtin_amdgcn_s_setprio(0);                                              \
    LOADV(_k0);                          /* issue V: softmax will cover it */   \
    if ((KN0_) >= 0) LOADK((KN0_), NKF0_, NKF1_);  /* issue next K */           \
    __builtin_amdgcn_sched_barrier(0);   /* pin load-issue point */             \
    if (DOMASK) {                                                               \
      _Pragma("unroll")                                                         \
      for (int _kb = 0; _kb < 4; ++_kb)                                         \
        _Pragma("unroll")                                                       \
        for (int _r = 0; _r < 4; ++_r) {                                        \
          int _kg = _k0 + _kb * 16 + 4 * g + _r;                                \
          if (_kg > qgA) stA[_kb][_r] = -1e30f;                                 \
          if (_kg > qgB) stB[_kb][_r] = -1e30f;                                 \
        }                                                                       \
    }                                                                           \
    float tmA = -1e30f, tmB = -1e30f;                                           \
    _Pragma("unroll")                                                           \
    for (int _kb = 0; _kb < 4; ++_kb)                                           \
      _Pragma("unroll")                                                         \
      for (int _r = 0; _r < 4; ++_r) {                                          \
        tmA = fmaxf(tmA, stA[_kb][_r]); tmB = fmaxf(tmB, stB[_kb][_r]);         \
      }                                                                         \
    tmA = fmaxf(tmA, __shfl_xor(tmA, 16)); tmA = fmaxf(tmA, __shfl_xor(tmA, 32));\
    tmB = fmaxf(tmB, __shfl_xor(tmB, 16)); tmB = fmaxf(tmB, __shfl_xor(tmB, 32));\
    if (!__all((tmA <= mA + 8.f) && (tmB <= mB + 8.f))) {                       \
      float mnA = fmaxf(mA, tmA), mnB = fmaxf(mB, tmB);                         \
      float alA = __expf(mA - mnA), alB = __expf(mB - mnB);                     \
      mA = mnA; mB = mnB;                                                       \
      lA *= alA; lB *= alB;                                                     \
      float alAr[4], alBr[4];                                                   \
      _Pragma("unroll")                                                         \
      for (int _r = 0; _r < 4; ++_r) {                                          \
        alAr[_r] = __shfl(alA, 4 * g + _r); alBr[_r] = __shfl(alB, 4 * g + _r); \
      }                                                                         \
      _Pragma("unroll")                                                         \
      for (int _db = 0; _db < 4; ++_db)                                         \
        _Pragma("unroll")                                                       \
        for (int _r = 0; _r < 4; ++_r) {                                        \
          accA[_db][_r] *= alAr[_r]; accB[_db][_r] *= alBr[_r];                 \
        }                                                                       \
    }                                                                           \
    float tsA = 0.f, tsB = 0.f;                                                 \
    _Pragma("unroll")                                                           \
    for (int _kb = 0; _kb < 4; ++_kb) {                                         \
      float pA0 = __expf(stA[_kb][0] - mA), pA1 = __expf(stA[_kb][1] - mA);     \
      float pA2 = __expf(stA[_kb][2] - mA), pA3 = __expf(stA[_kb][3] - mA);     \
      float pB0 = __expf(stB[_kb][0] - mB), pB1 = __expf(stB[_kb][1] - mB);     \
      float pB2 = __expf(stB[_kb][2] - mB), pB3 = __expf(stB[_kb][3] - mB);     \
      tsA += (pA0 + pA1) + (pA2 + pA3);                                         \
      tsB += (pB0 + pB1) + (pB2 + pB3);                                         \
      unsigned aLo, aHi, bLo, bHi;                                              \
      asm("v_cvt_pk_bf16_f32 %0, %1, %2" : "=v"(aLo) : "v"(pA0), "v"(pA1));     \
      asm("v_cvt_pk_bf16_f32 %0, %1, %2" : "=v"(aHi) : "v"(pA2), "v"(pA3));     \
      asm("v_cvt_pk_bf16_f32 %0, %1, %2" : "=v"(bLo) : "v"(pB0), "v"(pB1));     \
      asm("v_cvt_pk_bf16_f32 %0, %1, %2" : "=v"(bHi) : "v"(pB2), "v"(pB3));     \
      *(u32x2*)(Ps + rowA * 72 + _kb * 16 + 4 * g) = (u32x2){aLo, aHi};         \
      *(u32x2*)(Ps + rowB * 72 + _kb * 16 + 4 * g) = (u32x2){bLo, bHi};         \
    }                                                                           \
    tsA += __shfl_xor(tsA, 16); tsA += __shfl_xor(tsA, 32);                     \
    tsB += __shfl_xor(tsB, 16); tsB += __shfl_xor(tsB, 32);                     \
    lA += tsA; lB += tsB;                                                       \
    asm volatile("s_waitcnt lgkmcnt(0)" ::: "memory");                          \
    bf16x8 paA0 = *(const bf16x8*)(Ps + rowA * 72 + g * 8);                     \
    bf16x8 paA1 = *(const bf16x8*)(Ps + rowA * 72 + 32 + g * 8);                \
    bf16x8 paB0 = *(const bf16x8*)(Ps + rowB * 72 + g * 8);                     \
    bf16x8 paB1 = *(const bf16x8*)(Ps + rowB * 72 + 32 + g * 8);                \
    FENCE8(vf0, vf1);                    /* batch-wait V (mostly landed) */     \
    __builtin_amdgcn_s_setprio(1);                                              \
    _Pragma("unroll")                                                           \
    for (int _db = 0; _db < 4; ++_db) {                                         \
      accA[_db] = __builtin_amdgcn_mfma_f32_16x16x32_bf16(paA0, vf0[_db], accA[_db], 0, 0, 0); \
      accA[_db] = __builtin_amdgcn_mfma_f32_16x16x32_bf16(paA1, vf1[_db], accA[_db], 0, 0, 0); \
      accB[_db] = __builtin_amdgcn_mfma_f32_16x16x32_bf16(paB0, vf0[_db], accB[_db], 0, 0, 0); \
      accB[_db] = __builtin_amdgcn_mfma_f32_16x16x32_bf16(paB1, vf1[_db], accB[_db], 0, 0, 0); \
    }                                                                           \
    __builtin_amdgcn_s_setprio(0);                                              \
    if ((KN0_) >= 0) FENCE8(NKF0_, NKF1_);  /* batch-wait next K (covered) */   \
  } while (0)

  LOADK(0, kfa0, kfa1);
  FENCE8(kfa0, kfa1);
  for (int kt = 0; kt < nt; kt += 2) {
    const bool last = (kt == nt - 2);
    STEP(kt * 64,       kfa0, kfa1, (kt + 1) * 64,                       kfb0, kfb1, last);
    STEP((kt + 1) * 64, kfb0, kfb1, (kt + 2 < nt) ? (kt + 2) * 64 : -1,  kfa0, kfa1, last);
  }
#undef FENCE8
#undef LOADK
#undef LOADV
#undef STEP

  float invA = 1.0f / lA, invB = 1.0f / lB;
  float liA[4], liB[4];
  #pragma unroll
  for (int r = 0; r < 4; ++r) { liA[r] = __shfl(invA, 4 * g + r); liB[r] = __shfl(invB, 4 * g + r); }
  const int b = bh >> 4, h = bh & 15;
  #pragma unroll
  for (int db = 0; db < 4; ++db)
    #pragma unroll
    for (int r = 0; r < 4; ++r) {
      int mAo = q0 + 32 * w + 4 * g + r;
      int mBo = mAo + 16;
      O[((size_t)(b * T_ + mAo)) * E_ + h * 64 + db * 16 + lq] = f2bf(accA[db][r] * liA[r]);
      O[((size_t)(b * T_ + mBo)) * E_ + h * 64 + db * 16 + lq] = f2bf(accB[db][r] * liB[r]);
    }
}

extern "C" void kernel_launch(void* const* d_in, const int* in_sizes, int n_in,
                              void* d_out, int out_size, void* d_ws, size_t ws_size,
                              hipStream_t stream) {
  const float* x  = (const float*)d_in[0];
  const float* Wq = (const float*)d_in[1];
  const float* Wk = (const float*)d_in[2];
  const float* Wv = (const float*)d_in[3];
  const float* Wp = (const float*)d_in[4];
  const float* bp = (const float*)d_in[5];
  float* out = (float*)d_out;

  ushort_t* ws  = (ushort_t*)d_ws;
  ushort_t* xb  = ws;
  ushort_t* wqb = xb  + (size_t)M_ * E_;
  ushort_t* wkb = wqb + (size_t)E_ * E_;
  ushort_t* wvb = wkb + (size_t)E_ * E_;
  ushort_t* wpb = wvb + (size_t)E_ * E_;
  ushort_t* Qb  = wpb + (size_t)E_ * E_;
  ushort_t* Kb  = Qb  + (size_t)M_ * E_;
  ushort_t* Vb  = Kb  + (size_t)M_ * E_;
  ushort_t* Ab  = Vb  + (size_t)M_ * E_;

  conv_all<<<4096, 256, 0, stream>>>(x, Wq, Wk, Wv, Wp, xb, wqb, wkb, wvb, wpb);
  gemm_qkv<<<dim3(24, 32), 256, 0, stream>>>(xb, wqb, wkb, wvb, Qb, Kb, Vb);
  attn_mfma<<<512, 256, 0, stream>>>(Qb, Kb, Vb, Ab);
  gemm_out64<<<dim3(8, 64), 256, 0, stream>>>(Ab, wpb, bp, out);
}

// Round 14
// 122.828 us; speedup vs baseline: 1.7349x; 1.1046x over previous
//
#include <hip/hip_runtime.h>

#define T_ 2048
#define E_ 1024
#define H_ 16
#define D_ 64
#define M_ 4096   // B*T

typedef unsigned short ushort_t;
typedef __attribute__((ext_vector_type(8))) short bf16x8;
typedef __attribute__((ext_vector_type(4))) float f32x4;
typedef __attribute__((ext_vector_type(8))) unsigned short u16x8;
typedef __attribute__((ext_vector_type(2))) unsigned int u32x2;

__device__ __forceinline__ ushort_t f2bf(float f) {
  union { float f; unsigned u; } v; v.f = f;
  unsigned r = v.u + 0x7FFFu + ((v.u >> 16) & 1u);
  return (ushort_t)(r >> 16);
}

__device__ __forceinline__ void gl16(const void* g, void* l) {
  __builtin_amdgcn_global_load_lds((const __attribute__((address_space(1))) void*)g,
                                   (__attribute__((address_space(3))) void*)l, 16, 0, 0);
}

// ---------------- all f32->bf16 conversions in ONE launch ----------------
__global__ __launch_bounds__(256)
void conv_all(const float* __restrict__ x,  const float* __restrict__ wq,
              const float* __restrict__ wk, const float* __restrict__ wv,
              const float* __restrict__ wp,
              ushort_t* __restrict__ xb,  ushort_t* __restrict__ wqb,
              ushort_t* __restrict__ wkb, ushort_t* __restrict__ wvb,
              ushort_t* __restrict__ wpb)
{
  const int id = blockIdx.x;
  const float* s; ushort_t* d; size_t off;
  if (id < 2048) { s = x; d = xb; off = (size_t)id * 2048; }
  else {
    int wsel = (id - 2048) >> 9, wid = (id - 2048) & 511;
    off = (size_t)wid * 2048;
    s = wsel == 0 ? wq : wsel == 1 ? wk : wsel == 2 ? wv : wp;
    d = wsel == 0 ? wqb : wsel == 1 ? wkb : wsel == 2 ? wvb : wpb;
  }
  size_t i = off + (size_t)threadIdx.x * 8;
  float4 a = *(const float4*)(s + i);
  float4 b = *(const float4*)(s + i + 4);
  u16x8 o;
  o[0]=f2bf(a.x); o[1]=f2bf(a.y); o[2]=f2bf(a.z); o[3]=f2bf(a.w);
  o[4]=f2bf(b.x); o[5]=f2bf(b.y); o[6]=f2bf(b.z); o[7]=f2bf(b.w);
  *(u16x8*)(d + i) = o;
}

// ------- 128x128x(K=1024) bf16 GEMM core, Y = A @ W^T, 2-phase pipelined -------
__device__ __forceinline__ void gemm_core(const ushort_t* __restrict__ A,
                                          const ushort_t* __restrict__ W,
                                          int m0, int n0,
                                          ushort_t* As, ushort_t* Bs,
                                          f32x4 acc[4][4])
{
  const int t = threadIdx.x;
  const int lane = t & 63, w = t >> 6;
  const int g = lane >> 4, lq = lane & 15;
  const int wr = w >> 1, wc = w & 1;
  const int r0 = t >> 2;
  const int c0 = t & 3;
  const int ca0 = c0 ^ ((r0 >> 1) & 3);
  const int r1 = r0 + 64;
  const int ca1 = c0 ^ ((r1 >> 1) & 3);

  #pragma unroll
  for (int i = 0; i < 4; ++i)
    #pragma unroll
    for (int j = 0; j < 4; ++j) acc[i][j] = (f32x4){0.f,0.f,0.f,0.f};

  gl16(A + (size_t)(m0 + r0) * 1024 + ca0 * 8, As + t * 8);
  gl16(A + (size_t)(m0 + r1) * 1024 + ca1 * 8, As + 2048 + t * 8);
  gl16(W + (size_t)(n0 + r0) * 1024 + ca0 * 8, Bs + t * 8);
  gl16(W + (size_t)(n0 + r1) * 1024 + ca1 * 8, Bs + 2048 + t * 8);
  __syncthreads();

  int cur = 0;
  for (int k0 = 0; k0 < 1024; k0 += 32) {
    if (k0 + 32 < 1024) {
      const int nx = (cur ^ 1) * 4096;
      gl16(A + (size_t)(m0 + r0) * 1024 + k0 + 32 + ca0 * 8, As + nx + t * 8);
      gl16(A + (size_t)(m0 + r1) * 1024 + k0 + 32 + ca1 * 8, As + nx + 2048 + t * 8);
      gl16(W + (size_t)(n0 + r0) * 1024 + k0 + 32 + ca0 * 8, Bs + nx + t * 8);
      gl16(W + (size_t)(n0 + r1) * 1024 + k0 + 32 + ca1 * 8, Bs + nx + 2048 + t * 8);
    }
    const ushort_t* as = As + cur * 4096;
    const ushort_t* bs = Bs + cur * 4096;

    bf16x8 af[4], bfr[4];
    #pragma unroll
    for (int mi = 0; mi < 4; ++mi) {
      int row = wr * 64 + mi * 16 + lq;
      int ch = g ^ ((row >> 1) & 3);
      af[mi] = *(const bf16x8*)(as + row * 32 + ch * 8);
    }
    #pragma unroll
    for (int ni = 0; ni < 4; ++ni) {
      int row = wc * 64 + ni * 16 + lq;
      int ch = g ^ ((row >> 1) & 3);
      bfr[ni] = *(const bf16x8*)(bs + row * 32 + ch * 8);
    }
    __builtin_amdgcn_s_setprio(1);
    #pragma unroll
    for (int mi = 0; mi < 4; ++mi)
      #pragma unroll
      for (int ni = 0; ni < 4; ++ni)
        acc[mi][ni] = __builtin_amdgcn_mfma_f32_16x16x32_bf16(af[mi], bfr[ni], acc[mi][ni], 0, 0, 0);
    __builtin_amdgcn_s_setprio(0);

    __syncthreads();
    cur ^= 1;
  }
}

// Fused QKV projection. grid.x 0..23: sel = x>>3 (Q,K,V), n0 = (x&7)*128.
__global__ __launch_bounds__(256)
void gemm_qkv(const ushort_t* __restrict__ xb,
              const ushort_t* __restrict__ wqb, const ushort_t* __restrict__ wkb,
              const ushort_t* __restrict__ wvb,
              ushort_t* __restrict__ Qd, ushort_t* __restrict__ Kd, ushort_t* __restrict__ Vd)
{
  __shared__ __align__(16) ushort_t As[2 * 4096];
  __shared__ __align__(16) ushort_t Bs[2 * 4096];
  const int bx = blockIdx.x;
  const int sel = bx >> 3;
  const int n0 = (bx & 7) * 128;
  const int m0 = blockIdx.y * 128;
  const ushort_t* W = sel == 0 ? wqb : (sel == 1 ? wkb : wvb);
  f32x4 acc[4][4];
  gemm_core(xb, W, m0, n0, As, Bs, acc);

  const int t = threadIdx.x, lane = t & 63, w = t >> 6;
  const int g = lane >> 4, lq = lane & 15, wr = w >> 1, wc = w & 1;
  const float scl = (sel == 0) ? 0.125f : 1.0f;
  ushort_t* dst = sel == 0 ? Qd : (sel == 1 ? Kd : Vd);
  #pragma unroll
  for (int mi = 0; mi < 4; ++mi)
    #pragma unroll
    for (int ni = 0; ni < 4; ++ni)
      #pragma unroll
      for (int r = 0; r < 4; ++r) {
        int m = m0 + wr * 64 + mi * 16 + 4 * g + r;
        int n = n0 + wc * 64 + ni * 16 + lq;
        int b = m >> 11, tt = m & (T_ - 1);
        int h = n >> 6, d = n & (D_ - 1);
        ushort_t v = f2bf(acc[mi][ni][r] * scl);
        if (sel < 2) dst[((size_t)(b * H_ + h) * T_ + tt) * D_ + d] = v;
        else         dst[((size_t)(b * H_ + h) * D_ + d) * T_ + tt] = v;
      }
}

// Output projection, 64x128 tiles, 2-phase pipelined: out = Ab @ Wp^T + bp. grid (8, 64).
__global__ __launch_bounds__(256)
void gemm_out64(const ushort_t* __restrict__ Ab, const ushort_t* __restrict__ wpb,
                const float* __restrict__ bias, float* __restrict__ out)
{
  __shared__ __align__(16) ushort_t As[2 * 2048];
  __shared__ __align__(16) ushort_t Bs[2 * 4096];
  const int t = threadIdx.x, lane = t & 63, w = t >> 6;
  const int g = lane >> 4, lq = lane & 15;
  const int n0 = blockIdx.x * 128;
  const int m0 = blockIdx.y * 64;
  const int r0 = t >> 2, c0 = t & 3;
  const int ca0 = c0 ^ ((r0 >> 1) & 3);
  const int r1 = r0 + 64;
  const int ca1 = c0 ^ ((r1 >> 1) & 3);

  f32x4 acc[4][2];
  #pragma unroll
  for (int i = 0; i < 4; ++i) { acc[i][0] = (f32x4){0.f,0.f,0.f,0.f}; acc[i][1] = (f32x4){0.f,0.f,0.f,0.f}; }

  gl16(Ab  + (size_t)(m0 + r0) * 1024 + ca0 * 8, As + t * 8);
  gl16(wpb + (size_t)(n0 + r0) * 1024 + ca0 * 8, Bs + t * 8);
  gl16(wpb + (size_t)(n0 + r1) * 1024 + ca1 * 8, Bs + 2048 + t * 8);
  __syncthreads();

  int cur = 0;
  for (int k0 = 0; k0 < 1024; k0 += 32) {
    if (k0 + 32 < 1024) {
      gl16(Ab  + (size_t)(m0 + r0) * 1024 + k0 + 32 + ca0 * 8, As + (cur ^ 1) * 2048 + t * 8);
      gl16(wpb + (size_t)(n0 + r0) * 1024 + k0 + 32 + ca0 * 8, Bs + (cur ^ 1) * 4096 + t * 8);
      gl16(wpb + (size_t)(n0 + r1) * 1024 + k0 + 32 + ca1 * 8, Bs + (cur ^ 1) * 4096 + 2048 + t * 8);
    }
    const ushort_t* as = As + cur * 2048;
    const ushort_t* bs = Bs + cur * 4096;

    bf16x8 af[4], bfr[2];
    #pragma unroll
    for (int mi = 0; mi < 4; ++mi) {
      int row = mi * 16 + lq;
      int ch = g ^ ((row >> 1) & 3);
      af[mi] = *(const bf16x8*)(as + row * 32 + ch * 8);
    }
    #pragma unroll
    for (int ni = 0; ni < 2; ++ni) {
      int row = w * 32 + ni * 16 + lq;
      int ch = g ^ ((row >> 1) & 3);
      bfr[ni] = *(const bf16x8*)(bs + row * 32 + ch * 8);
    }
    __builtin_amdgcn_s_setprio(1);
    #pragma unroll
    for (int mi = 0; mi < 4; ++mi)
      #pragma unroll
      for (int ni = 0; ni < 2; ++ni)
        acc[mi][ni] = __builtin_amdgcn_mfma_f32_16x16x32_bf16(af[mi], bfr[ni], acc[mi][ni], 0, 0, 0);
    __builtin_amdgcn_s_setprio(0);

    __syncthreads();
    cur ^= 1;
  }
  #pragma unroll
  for (int mi = 0; mi < 4; ++mi)
    #pragma unroll
    for (int ni = 0; ni < 2; ++ni)
      #pragma unroll
      for (int r = 0; r < 4; ++r) {
        int m = m0 + mi * 16 + 4 * g + r;
        int n = n0 + w * 32 + ni * 16 + lq;
        out[(size_t)m * E_ + n] = acc[mi][ni][r] + bias[n];
      }
}

// -------- MFMA flash attention v10: LDS-shared K/V + counted vmcnt + raw barriers --------
// Rationale: the no-LDS design issued 128 global vector-loads per CU-step (TA-pipe
// saturated). Staging K/V in LDS shares them across 4 waves: 8 global_load_lds +
// 32 ds_read_b128 per block-step. Prefetch flies under compute; ONE vmcnt(0) after
// compute; raw s_barrier (no auto vmcnt drain). Staging/swizzle math = R5-verified;
// softmax/defer-max/cvt_pk/Ps = v4-verified; mapping/grid = v4-verified.
__global__ __launch_bounds__(256, 2)
void attn_mfma(const ushort_t* __restrict__ Q, const ushort_t* __restrict__ K,
               const ushort_t* __restrict__ Vt, ushort_t* __restrict__ O)
{
  __shared__ __align__(16) ushort_t Ks[2][4096];
  __shared__ __align__(16) ushort_t Vs[2][4096];
  __shared__ __align__(16) ushort_t Ps[128 * 72];
  const int t = threadIdx.x, w = t >> 6, lane = t & 63;
  const int g = lane >> 4, lq = lane & 15;
  const int i = blockIdx.x;
  const int xcd = i & 7, chunk = i >> 3;
  const int bh = xcd * 4 + (chunk >> 4);
  const int qt = (chunk < 32) ? (chunk & 15) : (15 - (chunk & 15));
  const int q0 = qt * 128;
  const size_t qkbase = (size_t)bh * T_ * D_;
  const size_t vbase  = (size_t)bh * D_ * T_;

  const int srow = t >> 3, sc = t & 7;
  const int cs0 = sc ^ (srow & 7);
  const int srow1 = srow + 32, cs1 = sc ^ (srow1 & 7);

  // Q fragments in registers (read once)
  const int rowA = 32 * w + lq, rowB = rowA + 16;
  const int qgA = q0 + rowA, qgB = q0 + rowB;
  const bf16x8 qA0 = *(const bf16x8*)(Q + qkbase + (size_t)qgA * D_ + g * 8);
  const bf16x8 qA1 = *(const bf16x8*)(Q + qkbase + (size_t)qgA * D_ + 32 + g * 8);
  const bf16x8 qB0 = *(const bf16x8*)(Q + qkbase + (size_t)qgB * D_ + g * 8);
  const bf16x8 qB1 = *(const bf16x8*)(Q + qkbase + (size_t)qgB * D_ + 32 + g * 8);

  f32x4 accA[4], accB[4];
  #pragma unroll
  for (int db = 0; db < 4; ++db) { accA[db] = (f32x4){0.f,0.f,0.f,0.f}; accB[db] = (f32x4){0.f,0.f,0.f,0.f}; }
  float mA = -1e30f, lA = 0.f, mB = -1e30f, lB = 0.f;

  const int nt = 2 * qt + 2;

  // prologue: stage tile 0 into buf 0; wait; sync
  gl16(K + qkbase + (size_t)srow  * D_ + cs0 * 8, &Ks[0][t * 8]);
  gl16(K + qkbase + (size_t)srow1 * D_ + cs1 * 8, &Ks[0][2048 + t * 8]);
  gl16(Vt + vbase + (size_t)srow  * T_ + cs0 * 8, &Vs[0][t * 8]);
  gl16(Vt + vbase + (size_t)srow1 * T_ + cs1 * 8, &Vs[0][2048 + t * 8]);
  asm volatile("s_waitcnt vmcnt(0)" ::: "memory");
  __builtin_amdgcn_s_barrier();

  for (int kt = 0; kt < nt; ++kt) {
    const int cur = kt & 1;
    const int k0 = kt * 64;
    if (kt + 1 < nt) {                 // prefetch next tile; loads stay in flight under compute
      const int kn = (kt + 1) * 64;
      gl16(K + qkbase + (size_t)(kn + srow)  * D_ + cs0 * 8, &Ks[cur ^ 1][t * 8]);
      gl16(K + qkbase + (size_t)(kn + srow1) * D_ + cs1 * 8, &Ks[cur ^ 1][2048 + t * 8]);
      gl16(Vt + vbase + (size_t)srow  * T_ + kn + cs0 * 8, &Vs[cur ^ 1][t * 8]);
      gl16(Vt + vbase + (size_t)srow1 * T_ + kn + cs1 * 8, &Vs[cur ^ 1][2048 + t * 8]);
    }
    const ushort_t* kb_ = &Ks[cur][0];
    const ushort_t* vb_ = &Vs[cur][0];

    // S^T = K . Q^T (shared K fragments from LDS; each feeds both q sub-blocks)
    f32x4 stA[4], stB[4];
    __builtin_amdgcn_s_setprio(1);
    #pragma unroll
    for (int kb = 0; kb < 4; ++kb) {
      int krow = kb * 16 + lq;
      bf16x8 ka0 = *(const bf16x8*)(kb_ + krow * 64 + ((g ^ (krow & 7)) * 8));
      bf16x8 ka1 = *(const bf16x8*)(kb_ + krow * 64 + (((4 + g) ^ (krow & 7)) * 8));
      f32x4 zA = (f32x4){0.f,0.f,0.f,0.f};
      zA = __builtin_amdgcn_mfma_f32_16x16x32_bf16(ka0, qA0, zA, 0, 0, 0);
      zA = __builtin_amdgcn_mfma_f32_16x16x32_bf16(ka1, qA1, zA, 0, 0, 0);
      stA[kb] = zA;
      f32x4 zB = (f32x4){0.f,0.f,0.f,0.f};
      zB = __builtin_amdgcn_mfma_f32_16x16x32_bf16(ka0, qB0, zB, 0, 0, 0);
      zB = __builtin_amdgcn_mfma_f32_16x16x32_bf16(ka1, qB1, zB, 0, 0, 0);
      stB[kb] = zB;
    }
    __builtin_amdgcn_s_setprio(0);

    if (kt >= nt - 2) {                // only diagonal-adjacent tiles mask
      #pragma unroll
      for (int kb = 0; kb < 4; ++kb)
        #pragma unroll
        for (int r = 0; r < 4; ++r) {
          int kg = k0 + kb * 16 + 4 * g + r;
          if (kg > qgA) stA[kb][r] = -1e30f;
          if (kg > qgB) stB[kb][r] = -1e30f;
        }
    }

    float tmA = -1e30f, tmB = -1e30f;
    #pragma unroll
    for (int kb = 0; kb < 4; ++kb)
      #pragma unroll
      for (int r = 0; r < 4; ++r) { tmA = fmaxf(tmA, stA[kb][r]); tmB = fmaxf(tmB, stB[kb][r]); }
    tmA = fmaxf(tmA, __shfl_xor(tmA, 16)); tmA = fmaxf(tmA, __shfl_xor(tmA, 32));
    tmB = fmaxf(tmB, __shfl_xor(tmB, 16)); tmB = fmaxf(tmB, __shfl_xor(tmB, 32));

    // defer-max: only rescale when a row's max grew by > 8 (wave-uniform branch)
    if (!__all((tmA <= mA + 8.f) && (tmB <= mB + 8.f))) {
      float mnA = fmaxf(mA, tmA), mnB = fmaxf(mB, tmB);
      float alA = __expf(mA - mnA), alB = __expf(mB - mnB);
      mA = mnA; mB = mnB;
      lA *= alA; lB *= alB;
      float alAr[4], alBr[4];
      #pragma unroll
      for (int r = 0; r < 4; ++r) { alAr[r] = __shfl(alA, 4 * g + r); alBr[r] = __shfl(alB, 4 * g + r); }
      #pragma unroll
      for (int db = 0; db < 4; ++db)
        #pragma unroll
        for (int r = 0; r < 4; ++r) { accA[db][r] *= alAr[r]; accB[db][r] *= alBr[r]; }
    }

    float tsA = 0.f, tsB = 0.f;
    #pragma unroll
    for (int kb = 0; kb < 4; ++kb) {
      float pA0 = __expf(stA[kb][0] - mA), pA1 = __expf(stA[kb][1] - mA);
      float pA2 = __expf(stA[kb][2] - mA), pA3 = __expf(stA[kb][3] - mA);
      float pB0 = __expf(stB[kb][0] - mB), pB1 = __expf(stB[kb][1] - mB);
      float pB2 = __expf(stB[kb][2] - mB), pB3 = __expf(stB[kb][3] - mB);
      tsA += (pA0 + pA1) + (pA2 + pA3);
      tsB += (pB0 + pB1) + (pB2 + pB3);
      unsigned aLo, aHi, bLo, bHi;
      asm("v_cvt_pk_bf16_f32 %0, %1, %2" : "=v"(aLo) : "v"(pA0), "v"(pA1));
      asm("v_cvt_pk_bf16_f32 %0, %1, %2" : "=v"(aHi) : "v"(pA2), "v"(pA3));
      asm("v_cvt_pk_bf16_f32 %0, %1, %2" : "=v"(bLo) : "v"(pB0), "v"(pB1));
      asm("v_cvt_pk_bf16_f32 %0, %1, %2" : "=v"(bHi) : "v"(pB2), "v"(pB3));
      *(u32x2*)(Ps + rowA * 72 + kb * 16 + 4 * g) = (u32x2){aLo, aHi};
      *(u32x2*)(Ps + rowB * 72 + kb * 16 + 4 * g) = (u32x2){bLo, bHi};
    }
    tsA += __shfl_xor(tsA, 16); tsA += __shfl_xor(tsA, 32);
    tsB += __shfl_xor(tsB, 16); tsB += __shfl_xor(tsB, 32);
    lA += tsA; lB += tsB;

    asm volatile("s_waitcnt lgkmcnt(0)" ::: "memory");   // own-wave Ps writes visible
    bf16x8 paA0 = *(const bf16x8*)(Ps + rowA * 72 + g * 8);
    bf16x8 paA1 = *(const bf16x8*)(Ps + rowA * 72 + 32 + g * 8);
    bf16x8 paB0 = *(const bf16x8*)(Ps + rowB * 72 + g * 8);
    bf16x8 paB1 = *(const bf16x8*)(Ps + rowB * 72 + 32 + g * 8);

    __builtin_amdgcn_s_setprio(1);
    #pragma unroll
    for (int db = 0; db < 4; ++db) {
      int vrow = db * 16 + lq;
      bf16x8 vb0 = *(const bf16x8*)(vb_ + vrow * 64 + ((g ^ (vrow & 7)) * 8));
      bf16x8 vb1 = *(const bf16x8*)(vb_ + vrow * 64 + (((4 + g) ^ (vrow & 7)) * 8));
      accA[db] = __builtin_amdgcn_mfma_f32_16x16x32_bf16(paA0, vb0, accA[db], 0, 0, 0);
      accA[db] = __builtin_amdgcn_mfma_f32_16x16x32_bf16(paA1, vb1, accA[db], 0, 0, 0);
      accB[db] = __builtin_amdgcn_mfma_f32_16x16x32_bf16(paB0, vb0, accB[db], 0, 0, 0);
      accB[db] = __builtin_amdgcn_mfma_f32_16x16x32_bf16(paB1, vb1, accB[db], 0, 0, 0);
    }
    __builtin_amdgcn_s_setprio(0);

    // counted-vmcnt discipline: drain ONLY the prefetch, after it flew under compute;
    // raw barrier (no compiler-forced full drain at a __syncthreads)
    if (kt + 1 < nt) asm volatile("s_waitcnt vmcnt(0)" ::: "memory");
    __builtin_amdgcn_s_barrier();
  }

  float invA = 1.0f / lA, invB = 1.0f / lB;
  float liA[4], liB[4];
  #pragma unroll
  for (int r = 0; r < 4; ++r) { liA[r] = __shfl(invA, 4 * g + r); liB[r] = __shfl(invB, 4 * g + r); }
  const int b = bh >> 4, h = bh & 15;
  #pragma unroll
  for (int db = 0; db < 4; ++db)
    #pragma unroll
    for (int r = 0; r < 4; ++r) {
      int mAo = q0 + 32 * w + 4 * g + r;
      int mBo = mAo + 16;
      O[((size_t)(b * T_ + mAo)) * E_ + h * 64 + db * 16 + lq] = f2bf(accA[db][r] * liA[r]);
      O[((size_t)(b * T_ + mBo)) * E_ + h * 64 + db * 16 + lq] = f2bf(accB[db][r] * liB[r]);
    }
}

extern "C" void kernel_launch(void* const* d_in, const int* in_sizes, int n_in,
                              void* d_out, int out_size, void* d_ws, size_t ws_size,
                              hipStream_t stream) {
  const float* x  = (const float*)d_in[0];
  const float* Wq = (const float*)d_in[1];
  const float* Wk = (const float*)d_in[2];
  const float* Wv = (const float*)d_in[3];
  const float* Wp = (const float*)d_in[4];
  const float* bp = (const float*)d_in[5];
  float* out = (float*)d_out;

  ushort_t* ws  = (ushort_t*)d_ws;
  ushort_t* xb  = ws;
  ushort_t* wqb = xb  + (size_t)M_ * E_;
  ushort_t* wkb = wqb + (size_t)E_ * E_;
  ushort_t* wvb = wkb + (size_t)E_ * E_;
  ushort_t* wpb = wvb + (size_t)E_ * E_;
  ushort_t* Qb  = wpb + (size_t)E_ * E_;
  ushort_t* Kb  = Qb  + (size_t)M_ * E_;
  ushort_t* Vb  = Kb  + (size_t)M_ * E_;
  ushort_t* Ab  = Vb  + (size_t)M_ * E_;

  conv_all<<<4096, 256, 0, stream>>>(x, Wq, Wk, Wv, Wp, xb, wqb, wkb, wvb, wpb);
  gemm_qkv<<<dim3(24, 32), 256, 0, stream>>>(xb, wqb, wkb, wvb, Qb, Kb, Vb);
  attn_mfma<<<512, 256, 0, stream>>>(Qb, Kb, Vb, Ab);
  gemm_out64<<<dim3(8, 64), 256, 0, stream>>>(Ab, wpb, bp, out);
}